// Round 10
// baseline (164.933 us; speedup 1.0000x reference)
//
#include <hip/hip_runtime.h>

// DmvCell RNN scan, B=32, T=2048, D=512. out[b][t] = [mean|var|max] (3*D).
// Compulsory: 128 MB in + 402 MB out.
// Proven: 2-kernel structure, per-wave sequential streams (R8 = 120.4us).
// Falsified: lookback fusion (R7), NC=128 (R9), occupancy/MLP theory (R2/R9),
// fold-traffic theory (R8 ~null), rw-batching (R8 ~null).
//
// R10 = R8 with ONE change (completing the {load,store}x{nt,reg} 2x2):
// phase C uses NT LOADS for x + REGULAR stores for out.
// Mechanism: regular stores take the L2 write-combined path fillBuffer
// proves at ~7 TB/s; nt loads don't allocate, so the re-read streams from
// L3-hits (while present) then HBM, without fighting the store stream in
// the caches. R5 (reg loads + reg stores) conflated store-path speed with
// L3 eviction of x; this isolates it.

#define BB 32
#define TT 2048
#define DD 512
#define NCHAIN (BB * DD)

typedef float f32x4 __attribute__((ext_vector_type(4)));

__device__ __forceinline__ float fast_rcp(float x) {
#if __has_builtin(__builtin_amdgcn_rcpf)
    return __builtin_amdgcn_rcpf(x);
#else
    return 1.0f / x;
#endif
}

__device__ __forceinline__ f32x4 vmax4(f32x4 a, f32x4 b) {
#if __has_builtin(__builtin_elementwise_max)
    return __builtin_elementwise_max(a, b);
#else
    f32x4 r;
    r.x = fmaxf(a.x, b.x); r.y = fmaxf(a.y, b.y);
    r.z = fmaxf(a.z, b.z); r.w = fmaxf(a.w, b.w);
    return r;
#endif
}

__device__ __forceinline__ f32x4 ntl(const float* p) {
#if __has_builtin(__builtin_nontemporal_load)
    return __builtin_nontemporal_load((const f32x4*)p);
#else
    return *(const f32x4*)p;
#endif
}

// Welford merge state: 8 chains (2 f32x4 halves) per lane.
struct St {
    float n;
    f32x4 s0, s1, m20, m21, mx0, mx1;
};

__device__ __forceinline__ void st_zero(St& r) {
    r.n = 0.f;
    r.s0 = r.s1 = r.m20 = r.m21 = r.mx0 = r.mx1 = (f32x4){0.f, 0.f, 0.f, 0.f};
}

// merge block (tn, ts*, tm*, tx*) into r; tn > 0. Ascending-order folds only.
__device__ __forceinline__ void st_merge(St& r, float tn, float itn,
                                         f32x4 ts0, f32x4 ts1,
                                         f32x4 tm0, f32x4 tm1,
                                         f32x4 tx0, f32x4 tx1) {
    if (r.n == 0.f) {   // uniform per wave
        r.n = tn;
        r.s0 = ts0; r.s1 = ts1;
        r.m20 = tm0; r.m21 = tm1;
        r.mx0 = tx0; r.mx1 = tx1;
    } else {
        float n     = r.n + tn;
        float irn   = fast_rcp(r.n);
        float scale = r.n * tn * fast_rcp(n);
        f32x4 da0 = ts0 * itn - r.s0 * irn;
        f32x4 da1 = ts1 * itn - r.s1 * irn;
        r.m20 += tm0 + da0 * da0 * scale;
        r.m21 += tm1 + da1 * da1 * scale;
        r.s0 += ts0; r.s1 += ts1;
        r.mx0 = vmax4(r.mx0, tx0); r.mx1 = vmax4(r.mx1, tx1);
        r.n = n;
    }
}

// ---------------- kernel 1: per-chunk aggregates (sequential reads) --------
template <int NC>
__launch_bounds__(256)
__global__ void dmv_agg_kernel(const float* __restrict__ x,
                               f32x4* __restrict__ ws4) {
    constexpr int CHUNK = TT / NC;
    f32x4* __restrict__ aS  = ws4;
    f32x4* __restrict__ aM2 = ws4 + (size_t)NC * 4096;
    f32x4* __restrict__ aMX = ws4 + 2 * (size_t)NC * 4096;

    const int tid = blockIdx.x * 256 + threadIdx.x;
    const int W   = tid >> 6;
    const int l   = tid & 63;
    const int c   = W & (NC - 1);
    const int b   = W / NC;

    const float* xp = x + ((size_t)(b * TT + c * CHUNK)) * DD + 4 * l;

    f32x4 s0 = {0,0,0,0}, s1 = {0,0,0,0};
    f32x4 q0 = {0,0,0,0}, q1 = {0,0,0,0};
    f32x4 m0 = {0,0,0,0}, m1 = {0,0,0,0};
    #pragma unroll 4
    for (int k = 0; k < CHUNK; ++k) {
        f32x4 a  = *(const f32x4*)(xp + (size_t)k * DD);
        f32x4 b2 = *(const f32x4*)(xp + (size_t)k * DD + 256);
        s0 += a;  q0 += a * a;   m0 = vmax4(m0, a);
        s1 += b2; q1 += b2 * b2; m1 = vmax4(m1, b2);
    }
    const size_t o = (size_t)c * 4096 + (size_t)b * 128 + l;
    const float ic = 1.0f / (float)CHUNK;
    aS[o]       = s0;  aS[o + 64]  = s1;
    aM2[o]      = q0 - s0 * s0 * ic;
    aM2[o + 64] = q1 - s1 * s1 * ic;
    aMX[o]      = m0;  aMX[o + 64] = m1;
}

// -------- kernel 2: coop prefix fold + batched rescan + regular stores -----
template <int NC>
__launch_bounds__(256)
__global__ void dmv_scan_fused(const float* __restrict__ x,
                               const f32x4* __restrict__ ws4,
                               float* __restrict__ out) {
    constexpr int CHUNK = TT / NC;
    constexpr int GRP   = NC / 4;          // chunk-groups per batch b
    const f32x4* __restrict__ aS  = ws4;
    const f32x4* __restrict__ aM2 = ws4 + (size_t)NC * 4096;
    const f32x4* __restrict__ aMX = ws4 + 2 * (size_t)NC * 4096;

    __shared__ f32x4 part[4][6][64];       // [wave][{s0,s1,m20,m21,mx0,mx1}][lane]

    const int tid = threadIdx.x;
    const int w   = tid >> 6;
    const int l   = tid & 63;
    const int g   = blockIdx.x & (GRP - 1);   // chunk-group within b
    const int b   = blockIdx.x / GRP;
    const int c0  = g * 4;
    const int c   = c0 + w;

    constexpr float icf = 1.0f / (float)CHUNK;

    // ---- cooperative fold of shared prefix [0, c0): wave w folds the
    //      quarter [w*g, (w+1)*g) (each quarter = g chunks, n = g*CHUNK) ----
    St q; st_zero(q);
    for (int j = w * g; j < (w + 1) * g; ++j) {
        const size_t oj = (size_t)j * 4096 + (size_t)b * 128 + l;
        st_merge(q, (float)CHUNK, icf,
                 aS[oj],  aS[oj + 64],
                 aM2[oj], aM2[oj + 64],
                 aMX[oj], aMX[oj + 64]);
    }
    part[w][0][l] = q.s0;  part[w][1][l] = q.s1;
    part[w][2][l] = q.m20; part[w][3][l] = q.m21;
    part[w][4][l] = q.mx0; part[w][5][l] = q.mx1;
    __syncthreads();

    // ---- my exclusive prefix = partials 0..3 (each n = g*CHUNK), then
    //      intra-block chunks c0..c-1 (each n = CHUNK), ascending order ----
    St r; st_zero(r);
    if (g > 0) {
        const float qn  = (float)(g * CHUNK);
        const float iqn = fast_rcp(qn);
        #pragma unroll
        for (int ww = 0; ww < 4; ++ww) {
            st_merge(r, qn, iqn,
                     part[ww][0][l], part[ww][1][l],
                     part[ww][2][l], part[ww][3][l],
                     part[ww][4][l], part[ww][5][l]);
        }
    }
    for (int j = c0; j < c; ++j) {
        const size_t oj = (size_t)j * 4096 + (size_t)b * 128 + l;
        st_merge(r, (float)CHUNK, icf,
                 aS[oj],  aS[oj + 64],
                 aM2[oj], aM2[oj + 64],
                 aMX[oj], aMX[oj + 64]);
    }

    float cnt = r.n;  // == c * CHUNK
    f32x4 rs0 = r.s0, rs1 = r.s1, rm20 = r.m20, rm21 = r.m21;
    f32x4 rmx0 = r.mx0, rmx1 = r.mx1;
    f32x4 rmean0 = {0,0,0,0}, rmean1 = {0,0,0,0};
    if (c > 0) {
        float icnt = fast_rcp(cnt);
        rmean0 = rs0 * icnt;
        rmean1 = rs1 * icnt;
    }

    // ---- phase C: exact rescan; NT loads (no cache allocate) + REGULAR
    //      stores (L2 write-combined path, fillBuffer-proven ~7 TB/s) ----
    const float* xp = x   + ((size_t)(b * TT + c * CHUNK)) * DD + 4 * l;
    float*       op = out + ((size_t)(b * TT + c * CHUNK)) * (3 * DD) + 4 * l;

    for (int kb = 0; kb < CHUNK; kb += 4) {
        f32x4 v[8];
        #pragma unroll
        for (int k4 = 0; k4 < 4; ++k4) {
            v[2 * k4]     = ntl(xp + (size_t)(kb + k4) * DD);
            v[2 * k4 + 1] = ntl(xp + (size_t)(kb + k4) * DD + 256);
        }
        #pragma unroll
        for (int k4 = 0; k4 < 4; ++k4) {
            f32x4 v0 = v[2 * k4], v1 = v[2 * k4 + 1];
            cnt += 1.f;
            float inv = fast_rcp(cnt);
            rs0 += v0; rs1 += v1;
            rmx0 = vmax4(rmx0, v0); rmx1 = vmax4(rmx1, v1);
            f32x4 nm0 = rs0 * inv, nm1 = rs1 * inv;
            rm20 += (v0 - rmean0) * (v0 - nm0);
            rm21 += (v1 - rmean1) * (v1 - nm1);
            rmean0 = nm0; rmean1 = nm1;
            f32x4 var0 = rm20 * inv, var1 = rm21 * inv;
            float* row = op + (size_t)(kb + k4) * (3 * DD);
            *(f32x4*)(row)        = nm0;   *(f32x4*)(row + 256)  = nm1;
            *(f32x4*)(row + 512)  = var0;  *(f32x4*)(row + 768)  = var1;
            *(f32x4*)(row + 1024) = rmx0;  *(f32x4*)(row + 1280) = rmx1;
        }
    }
}

// ---------------- fallback (R2, proven): single kernel, LDS merge ----------
#define FNW 16
#define FCHUNK (TT / FNW)
#define DGRP 64

__launch_bounds__(1024, 1)
__global__ void dmv_scan_fallback(const float* __restrict__ x,
                                  float* __restrict__ out) {
    __shared__ float aggS[FNW][DGRP];
    __shared__ float aggM2[FNW][DGRP];
    __shared__ float aggMX[FNW][DGRP];

    const int tid = threadIdx.x;
    const int w   = tid >> 6;
    const int l   = tid & 63;
    const int b   = blockIdx.x >> 3;
    const int d0  = (blockIdx.x & 7) * DGRP;

    const float* xp = x   + ((size_t)b * TT) * DD + d0 + l
                          + (size_t)(w * FCHUNK) * DD;
    float*       op = out + ((size_t)b * TT) * (3 * DD) + d0 + l
                          + (size_t)(w * FCHUNK) * (3 * DD);

    if (w < FNW - 1) {
        float s = 0.f, ss = 0.f, mx = 0.f;
        #pragma unroll 8
        for (int k = 0; k < FCHUNK; ++k) {
            float xv = xp[(size_t)k * DD];
            s += xv; ss = fmaf(xv, xv, ss); mx = fmaxf(mx, xv);
        }
        aggS[w][l] = s;
        aggM2[w][l] = ss - s * s * (1.0f / FCHUNK);
        aggMX[w][l] = mx;
    }
    __syncthreads();

    float c_n = 0.f, c_s = 0.f, c_m2 = 0.f, c_mx = 0.f;
    for (int j = 0; j < w; ++j) {
        float bs = aggS[j][l], bm2 = aggM2[j][l], bmx = aggMX[j][l];
        if (j == 0) {
            c_n = (float)FCHUNK; c_s = bs; c_m2 = bm2; c_mx = bmx;
        } else {
            float n  = c_n + (float)FCHUNK;
            float da = bs * (1.0f / FCHUNK) - c_s / c_n;
            c_m2 = c_m2 + bm2 + da * da * (c_n * (float)FCHUNK / n);
            c_s += bs; c_mx = fmaxf(c_mx, bmx); c_n = n;
        }
    }

    float cnt = c_n, rs = c_s, rm2 = c_m2, rmx = c_mx;
    float rmean = (w > 0) ? rs / cnt : 0.f;
    #pragma unroll 8
    for (int k = 0; k < FCHUNK; ++k) {
        float xv = xp[(size_t)k * DD];
        cnt += 1.f;
        float inv = fast_rcp(cnt);
        rs += xv; rmx = fmaxf(rmx, xv);
        float nm = rs * inv;
        rm2 += (xv - rmean) * (xv - nm);
        rmean = nm;
        float var = rm2 * inv;
        float* orow = op + (size_t)k * (3 * DD);
        orow[0] = nm; orow[DD] = var; orow[2 * DD] = rmx;
    }
}

// ---------------- launcher ----------------
template <int NC>
static void launch_2k(const float* x, float* out, void* d_ws, hipStream_t stream) {
    dim3 blk(256);
    dmv_agg_kernel<NC><<<dim3(8 * NC), blk, 0, stream>>>(x, (f32x4*)d_ws);
    dmv_scan_fused<NC><<<dim3(8 * NC), blk, 0, stream>>>(x, (const f32x4*)d_ws, out);
}

extern "C" void kernel_launch(void* const* d_in, const int* in_sizes, int n_in,
                              void* d_out, int out_size, void* d_ws, size_t ws_size,
                              hipStream_t stream) {
    (void)in_sizes; (void)n_in; (void)out_size;
    const float* x = (const float*)d_in[0];
    float* out = (float*)d_out;

    const size_t need64 = (size_t)3 * 64 * 4096 * sizeof(f32x4);  // 12.6 MB
    const size_t need32 = (size_t)3 * 32 * 4096 * sizeof(f32x4);  //  6.3 MB

    if (d_ws && ws_size >= need64) {
        launch_2k<64>(x, out, d_ws, stream);
    } else if (d_ws && ws_size >= need32) {
        launch_2k<32>(x, out, d_ws, stream);
    } else {
        dmv_scan_fallback<<<dim3(BB * (DD / DGRP)), dim3(1024), 0, stream>>>(x, out);
    }
}

// Round 11
// 118.687 us; speedup vs baseline: 1.3896x; 1.3896x over previous
//
#include <hip/hip_runtime.h>

// DmvCell RNN scan, B=32, T=2048, D=512. out[b][t] = [mean|var|max] (3*D).
// Compulsory: 128 MB in + 402 MB nt-out.
// Proven: 2-kernel structure, nt stores + regular loads (R8 = 120.4us).
// Falsified: fusion (R7), NC=128 (R9), reg stores (R5/R10), nt loads (R10),
// fold traffic (R8), rw batching (R8).
//
// R11 = R8 with the scan kernel D-SPLIT 2x: each chunk is handled by TWO
// waves, one per 256-float half-row -> 4096 scan waves (4/SIMD, 2x R8)
// at UNCHANGED table size / fold traffic (the un-confounded occupancy
// probe R9 failed to be). Mechanism: vmcnt orders load-waits behind
// prior nt-store acks; more waves/SIMD hides that serialization.

#define BB 32
#define TT 2048
#define DD 512
#define NCHAIN (BB * DD)

typedef float f32x4 __attribute__((ext_vector_type(4)));

__device__ __forceinline__ float fast_rcp(float x) {
#if __has_builtin(__builtin_amdgcn_rcpf)
    return __builtin_amdgcn_rcpf(x);
#else
    return 1.0f / x;
#endif
}

__device__ __forceinline__ f32x4 vmax4(f32x4 a, f32x4 b) {
#if __has_builtin(__builtin_elementwise_max)
    return __builtin_elementwise_max(a, b);
#else
    f32x4 r;
    r.x = fmaxf(a.x, b.x); r.y = fmaxf(a.y, b.y);
    r.z = fmaxf(a.z, b.z); r.w = fmaxf(a.w, b.w);
    return r;
#endif
}

__device__ __forceinline__ void nts(f32x4 v, float* p) {
#if __has_builtin(__builtin_nontemporal_store)
    __builtin_nontemporal_store(v, (f32x4*)p);
#else
    *(f32x4*)p = v;
#endif
}

// Half-row Welford state: 4 chains (1 f32x4) per lane.
struct St1 {
    float n;
    f32x4 s, m2, mx;
};

__device__ __forceinline__ void st1_zero(St1& r) {
    r.n = 0.f;
    r.s = r.m2 = r.mx = (f32x4){0.f, 0.f, 0.f, 0.f};
}

// merge block (tn, ts, tm, tx) into r; tn > 0. Ascending-order folds only.
__device__ __forceinline__ void st1_merge(St1& r, float tn, float itn,
                                          f32x4 ts, f32x4 tm, f32x4 tx) {
    if (r.n == 0.f) {   // uniform per wave
        r.n = tn; r.s = ts; r.m2 = tm; r.mx = tx;
    } else {
        float n     = r.n + tn;
        float irn   = fast_rcp(r.n);
        float scale = r.n * tn * fast_rcp(n);
        f32x4 da = ts * itn - r.s * irn;
        r.m2 += tm + da * da * scale;
        r.s += ts;
        r.mx = vmax4(r.mx, tx);
        r.n = n;
    }
}

// ---------------- kernel 1: per-chunk aggregates (unchanged from R8) -------
template <int NC>
__launch_bounds__(256)
__global__ void dmv_agg_kernel(const float* __restrict__ x,
                               f32x4* __restrict__ ws4) {
    constexpr int CHUNK = TT / NC;
    f32x4* __restrict__ aS  = ws4;
    f32x4* __restrict__ aM2 = ws4 + (size_t)NC * 4096;
    f32x4* __restrict__ aMX = ws4 + 2 * (size_t)NC * 4096;

    const int tid = blockIdx.x * 256 + threadIdx.x;
    const int W   = tid >> 6;
    const int l   = tid & 63;
    const int c   = W & (NC - 1);
    const int b   = W / NC;

    const float* xp = x + ((size_t)(b * TT + c * CHUNK)) * DD + 4 * l;

    f32x4 s0 = {0,0,0,0}, s1 = {0,0,0,0};
    f32x4 q0 = {0,0,0,0}, q1 = {0,0,0,0};
    f32x4 m0 = {0,0,0,0}, m1 = {0,0,0,0};
    #pragma unroll 4
    for (int k = 0; k < CHUNK; ++k) {
        f32x4 a  = *(const f32x4*)(xp + (size_t)k * DD);
        f32x4 b2 = *(const f32x4*)(xp + (size_t)k * DD + 256);
        s0 += a;  q0 += a * a;   m0 = vmax4(m0, a);
        s1 += b2; q1 += b2 * b2; m1 = vmax4(m1, b2);
    }
    const size_t o = (size_t)c * 4096 + (size_t)b * 128 + l;
    const float ic = 1.0f / (float)CHUNK;
    aS[o]       = s0;  aS[o + 64]  = s1;
    aM2[o]      = q0 - s0 * s0 * ic;
    aM2[o + 64] = q1 - s1 * s1 * ic;
    aMX[o]      = m0;  aMX[o + 64] = m1;
}

// -------- kernel 2: D-split coop fold + rescan + nt stores -----------------
// 512 threads = 8 waves = 4 chunks x 2 D-halves. wave w: chunk cw=w>>1,
// half h=w&1. Same merge tree per half as R8 (halves are independent).
template <int NC>
__launch_bounds__(512)
__global__ void dmv_scan_split(const float* __restrict__ x,
                               const f32x4* __restrict__ ws4,
                               float* __restrict__ out) {
    constexpr int CHUNK = TT / NC;
    constexpr int GRP   = NC / 4;          // blocks per batch b
    const f32x4* __restrict__ aS  = ws4;
    const f32x4* __restrict__ aM2 = ws4 + (size_t)NC * 4096;
    const f32x4* __restrict__ aMX = ws4 + 2 * (size_t)NC * 4096;

    __shared__ f32x4 part[8][3][64];       // [wave][{s,m2,mx}][lane]

    const int tid = threadIdx.x;
    const int w   = tid >> 6;              // 0..7
    const int l   = tid & 63;
    const int h   = w & 1;                 // D-half
    const int cw  = w >> 1;                // chunk within block (0..3)
    const int g   = blockIdx.x & (GRP - 1);
    const int b   = blockIdx.x / GRP;
    const int c0  = g * 4;
    const int c   = c0 + cw;

    constexpr float icf = 1.0f / (float)CHUNK;
    const int hofs = 64 * h;               // table offset for my half

    // ---- cooperative fold of shared prefix [0, c0): wave (cw,h) folds
    //      quarter [cw*g, (cw+1)*g) of half h ----
    St1 q; st1_zero(q);
    for (int j = cw * g; j < (cw + 1) * g; ++j) {
        const size_t oj = (size_t)j * 4096 + (size_t)b * 128 + l + hofs;
        st1_merge(q, (float)CHUNK, icf, aS[oj], aM2[oj], aMX[oj]);
    }
    part[w][0][l] = q.s; part[w][1][l] = q.m2; part[w][2][l] = q.mx;
    __syncthreads();

    // ---- my exclusive prefix: partials of my half in ascending chunk
    //      order (waves 2*qq+h), then intra-block chunks c0..c-1 ----
    St1 r; st1_zero(r);
    if (g > 0) {
        const float qn  = (float)(g * CHUNK);
        const float iqn = fast_rcp(qn);
        #pragma unroll
        for (int qq = 0; qq < 4; ++qq) {
            const int pw = 2 * qq + h;
            st1_merge(r, qn, iqn, part[pw][0][l], part[pw][1][l], part[pw][2][l]);
        }
    }
    for (int j = c0; j < c; ++j) {
        const size_t oj = (size_t)j * 4096 + (size_t)b * 128 + l + hofs;
        st1_merge(r, (float)CHUNK, icf, aS[oj], aM2[oj], aMX[oj]);
    }

    float cnt = r.n;  // == c * CHUNK
    f32x4 rs = r.s, rm2 = r.m2, rmx = r.mx;
    f32x4 rmean = {0,0,0,0};
    if (c > 0) rmean = rs * fast_rcp(cnt);

    // ---- exact sequential rescan of own (chunk, half); nt stores ----
    const float* xp = x   + ((size_t)(b * TT + c * CHUNK)) * DD + h * 256 + 4 * l;
    float*       op = out + ((size_t)(b * TT + c * CHUNK)) * (3 * DD) + h * 256 + 4 * l;

    #pragma unroll 4
    for (int k = 0; k < CHUNK; ++k) {
        f32x4 v = *(const f32x4*)(xp + (size_t)k * DD);
        cnt += 1.f;
        float inv = fast_rcp(cnt);
        rs += v;
        rmx = vmax4(rmx, v);
        f32x4 nm = rs * inv;
        rm2 += (v - rmean) * (v - nm);
        rmean = nm;
        f32x4 var = rm2 * inv;
        float* row = op + (size_t)k * (3 * DD);
        nts(nm,  row);
        nts(var, row + 512);
        nts(rmx, row + 1024);
    }
}

// ---------------- fallback (R2, proven): single kernel, LDS merge ----------
#define FNW 16
#define FCHUNK (TT / FNW)
#define DGRP 64

__launch_bounds__(1024, 1)
__global__ void dmv_scan_fallback(const float* __restrict__ x,
                                  float* __restrict__ out) {
    __shared__ float aggS[FNW][DGRP];
    __shared__ float aggM2[FNW][DGRP];
    __shared__ float aggMX[FNW][DGRP];

    const int tid = threadIdx.x;
    const int w   = tid >> 6;
    const int l   = tid & 63;
    const int b   = blockIdx.x >> 3;
    const int d0  = (blockIdx.x & 7) * DGRP;

    const float* xp = x   + ((size_t)b * TT) * DD + d0 + l
                          + (size_t)(w * FCHUNK) * DD;
    float*       op = out + ((size_t)b * TT) * (3 * DD) + d0 + l
                          + (size_t)(w * FCHUNK) * (3 * DD);

    if (w < FNW - 1) {
        float s = 0.f, ss = 0.f, mx = 0.f;
        #pragma unroll 8
        for (int k = 0; k < FCHUNK; ++k) {
            float xv = xp[(size_t)k * DD];
            s += xv; ss = fmaf(xv, xv, ss); mx = fmaxf(mx, xv);
        }
        aggS[w][l] = s;
        aggM2[w][l] = ss - s * s * (1.0f / FCHUNK);
        aggMX[w][l] = mx;
    }
    __syncthreads();

    float c_n = 0.f, c_s = 0.f, c_m2 = 0.f, c_mx = 0.f;
    for (int j = 0; j < w; ++j) {
        float bs = aggS[j][l], bm2 = aggM2[j][l], bmx = aggMX[j][l];
        if (j == 0) {
            c_n = (float)FCHUNK; c_s = bs; c_m2 = bm2; c_mx = bmx;
        } else {
            float n  = c_n + (float)FCHUNK;
            float da = bs * (1.0f / FCHUNK) - c_s / c_n;
            c_m2 = c_m2 + bm2 + da * da * (c_n * (float)FCHUNK / n);
            c_s += bs; c_mx = fmaxf(c_mx, bmx); c_n = n;
        }
    }

    float cnt = c_n, rs = c_s, rm2 = c_m2, rmx = c_mx;
    float rmean = (w > 0) ? rs / cnt : 0.f;
    #pragma unroll 8
    for (int k = 0; k < FCHUNK; ++k) {
        float xv = xp[(size_t)k * DD];
        cnt += 1.f;
        float inv = fast_rcp(cnt);
        rs += xv; rmx = fmaxf(rmx, xv);
        float nm = rs * inv;
        rm2 += (xv - rmean) * (xv - nm);
        rmean = nm;
        float var = rm2 * inv;
        float* orow = op + (size_t)k * (3 * DD);
        orow[0] = nm; orow[DD] = var; orow[2 * DD] = rmx;
    }
}

// ---------------- launcher ----------------
template <int NC>
static void launch_2k(const float* x, float* out, void* d_ws, hipStream_t stream) {
    dmv_agg_kernel<NC><<<dim3(8 * NC), dim3(256), 0, stream>>>(x, (f32x4*)d_ws);
    // scan: NC/4 chunk-groups per b x 32 b blocks of 512 threads (8 waves)
    dmv_scan_split<NC><<<dim3(8 * NC), dim3(512), 0, stream>>>(
        x, (const f32x4*)d_ws, out);
}

extern "C" void kernel_launch(void* const* d_in, const int* in_sizes, int n_in,
                              void* d_out, int out_size, void* d_ws, size_t ws_size,
                              hipStream_t stream) {
    (void)in_sizes; (void)n_in; (void)out_size;
    const float* x = (const float*)d_in[0];
    float* out = (float*)d_out;

    const size_t need64 = (size_t)3 * 64 * 4096 * sizeof(f32x4);  // 12.6 MB
    const size_t need32 = (size_t)3 * 32 * 4096 * sizeof(f32x4);  //  6.3 MB

    if (d_ws && ws_size >= need64) {
        launch_2k<64>(x, out, d_ws, stream);
    } else if (d_ws && ws_size >= need32) {
        launch_2k<32>(x, out, d_ws, stream);
    } else {
        dmv_scan_fallback<<<dim3(BB * (DD / DGRP)), dim3(1024), 0, stream>>>(x, out);
    }
}